// Round 1
// baseline (317.017 us; speedup 1.0000x reference)
//
#include <hip/hip_runtime.h>
#include <stdint.h>

#define T_TOK 8192
#define NEXP  8
#define DIMSZ 1024
#define HIDSZ 2048

typedef __attribute__((ext_vector_type(4))) float f32x4;
typedef __attribute__((ext_vector_type(8))) short s16x8;

// ---------- helpers ----------

__device__ __forceinline__ uint16_t f2bf(float f) {
  uint32_t u = __builtin_bit_cast(uint32_t, f);
  u += 0x7fffu + ((u >> 16) & 1u);   // RNE (NaN not expected in this problem)
  return (uint16_t)(u >> 16);
}

// async global->LDS, 16B per lane. LDS destination is wave-uniform base +
// lane*16 (HW semantics, learn_hip m104/m108): pass only the uniform base.
__device__ __forceinline__ void gload_lds16(const uint16_t* g, const uint16_t* lds_base) {
  __builtin_amdgcn_global_load_lds(
      (const __attribute__((address_space(1))) uint32_t*)(uintptr_t)g,
      (__attribute__((address_space(3))) uint32_t*)(uint32_t)(uintptr_t)lds_base,
      16, 0, 0);
}

// ---------- kernels ----------

__global__ void cvt_f32_to_bf16(const float* __restrict__ in,
                                uint16_t* __restrict__ out, int n8) {
  int stride = gridDim.x * blockDim.x;
  for (int i = blockIdx.x * blockDim.x + threadIdx.x; i < n8; i += stride) {
    const float4* p = (const float4*)in + 2 * (size_t)i;
    float4 a = p[0], b = p[1];
    uint4 o;
    o.x = f2bf(a.x) | ((uint32_t)f2bf(a.y) << 16);
    o.y = f2bf(a.z) | ((uint32_t)f2bf(a.w) << 16);
    o.z = f2bf(b.x) | ((uint32_t)f2bf(b.y) << 16);
    o.w = f2bf(b.z) | ((uint32_t)f2bf(b.w) << 16);
    ((uint4*)out)[i] = o;
  }
}

__global__ void offs_kernel(const int* __restrict__ counts, int* __restrict__ offs) {
  if (threadIdx.x == 0 && blockIdx.x == 0) {
    int s = 0;
    for (int e = 0; e < NEXP; ++e) { offs[e] = s; s += counts[e]; }
    offs[NEXP] = s;
  }
}

// Grouped NT GEMM: C[m, n] = sum_k A[m, k] * B_e[n, k]
// A: [T_TOK, K] bf16 row-major (rows grouped by expert)
// B: [NEXP, N, K] bf16
// C: [T_TOK, N] (bf16 if OUT_BF16, else f32 rounded through bf16)
// Tile 128x128, BK=32, 256 threads (4 waves, 2x2 of 64x64 per wave).
template <bool OUT_BF16>
__global__ void gemm_grouped(const uint16_t* __restrict__ A,
                             const uint16_t* __restrict__ B,
                             void* __restrict__ C,
                             const int* __restrict__ offs,
                             int N, int K) {
  __shared__ __align__(16) uint16_t As[128 * 32];  // 8 KB, unpadded (global_load_lds layout)
  __shared__ __align__(16) uint16_t Bs[128 * 32];  // 8 KB

  const int maxMT = T_TOK / 128;
  const int e  = blockIdx.y / maxMT;
  const int mt = blockIdx.y % maxMT;
  const int m_start = offs[e];
  const int m_count = offs[e + 1] - m_start;
  const int m0 = mt * 128;
  if (m0 >= m_count) return;                 // block-uniform early exit
  int valid_m = m_count - m0;
  if (valid_m > 128) valid_m = 128;
  const int n0 = blockIdx.x * 128;

  const int tid  = threadIdx.x;
  const int w    = tid >> 6;
  const int lane = tid & 63;
  const int wm = w & 1, wn = w >> 1;

  // Staging map: tile is row-major [128][32] bf16 = 8 KB = 8 chunks of 1 KB.
  // Wave w fills chunks w and w+4. Within chunk c, lane l supplies the 16 B
  // at LDS byte c*1024 + l*16  ->  elem c*512 + l*8  ->  row c*16 + l/4,
  // col (l&3)*8.
  const int srow0 = w * 16 + (lane >> 2);
  const int srow1 = (w + 4) * 16 + (lane >> 2);
  const int scol  = (lane & 3) * 8;

  const uint16_t* gA = A + (size_t)m_start * K;
  const uint16_t* gB = B + (size_t)e * N * K;

  // clamp A rows for partial tiles (dup rows are computed but never stored)
  const int ar0 = m0 + (srow0 < valid_m ? srow0 : valid_m - 1);
  const int ar1 = m0 + (srow1 < valid_m ? srow1 : valid_m - 1);

  const uint16_t* a0p = gA + (size_t)ar0 * K + scol;
  const uint16_t* a1p = gA + (size_t)ar1 * K + scol;
  const uint16_t* b0p = gB + (size_t)(n0 + srow0) * K + scol;
  const uint16_t* b1p = gB + (size_t)(n0 + srow1) * K + scol;

  const uint16_t* lA0 = &As[w * 512];
  const uint16_t* lA1 = &As[(w + 4) * 512];
  const uint16_t* lB0 = &Bs[w * 512];
  const uint16_t* lB1 = &Bs[(w + 4) * 512];

  // MFMA fragment addresses (16x16x32): lane holds A[m=lane&15][k=quad*8+j]
  const int fr = lane & 15;
  const int fk = (lane >> 4) * 8;

  f32x4 acc[4][4];
#pragma unroll
  for (int mi = 0; mi < 4; ++mi)
#pragma unroll
    for (int ni = 0; ni < 4; ++ni) acc[mi][ni] = (f32x4){0.f, 0.f, 0.f, 0.f};

  for (int k0 = 0; k0 < K; k0 += 32) {
    __syncthreads();  // previous iter's ds_reads done before overwrite
    gload_lds16(a0p, lA0);
    gload_lds16(a1p, lA1);
    gload_lds16(b0p, lB0);
    gload_lds16(b1p, lB1);
    a0p += 32; a1p += 32; b0p += 32; b1p += 32;
    __syncthreads();  // vmcnt(0) drain: tiles resident

    s16x8 af[4], bf[4];
#pragma unroll
    for (int mi = 0; mi < 4; ++mi)
      af[mi] = *(const s16x8*)&As[(wm * 64 + mi * 16 + fr) * 32 + fk];
#pragma unroll
    for (int ni = 0; ni < 4; ++ni)
      bf[ni] = *(const s16x8*)&Bs[(wn * 64 + ni * 16 + fr) * 32 + fk];
#pragma unroll
    for (int mi = 0; mi < 4; ++mi)
#pragma unroll
      for (int ni = 0; ni < 4; ++ni)
        acc[mi][ni] = __builtin_amdgcn_mfma_f32_16x16x32_bf16(af[mi], bf[ni], acc[mi][ni], 0, 0, 0);
  }

  // Epilogue. C/D layout (16x16): col = lane&15, row = (lane>>4)*4 + reg.
  const int cq = (lane >> 4) * 4;
  const int cc = lane & 15;
#pragma unroll
  for (int mi = 0; mi < 4; ++mi) {
#pragma unroll
    for (int r = 0; r < 4; ++r) {
      const int rt = wm * 64 + mi * 16 + cq + r;
      if (rt < valid_m) {
        const size_t rowoff = (size_t)(m_start + m0 + rt) * N;
#pragma unroll
        for (int ni = 0; ni < 4; ++ni) {
          const int col = n0 + wn * 64 + ni * 16 + cc;
          const float v = acc[mi][ni][r];
          if (OUT_BF16) {
            ((uint16_t*)C)[rowoff + col] = f2bf(v);
          } else {
            // match reference: final value went through bf16
            const uint32_t b = (uint32_t)f2bf(v) << 16;
            ((float*)C)[rowoff + col] = __builtin_bit_cast(float, b);
          }
        }
      }
    }
  }
}

// ---------- launch ----------

extern "C" void kernel_launch(void* const* d_in, const int* in_sizes, int n_in,
                              void* d_out, int out_size, void* d_ws, size_t ws_size,
                              hipStream_t stream) {
  const float* x  = (const float*)d_in[0];   // [T, DIM]
  const float* w1 = (const float*)d_in[1];   // [E, HID, DIM]
  const float* w2 = (const float*)d_in[2];   // [E, DIM, HID]
  const int* cnt  = (const int*)d_in[3];     // [E]
  float* out = (float*)d_out;                // [T, DIM] f32

  char* ws = (char*)d_ws;
  uint16_t* xb  = (uint16_t*)(ws);                      // 16 MB  [T, DIM] bf16
  uint16_t* w1b = (uint16_t*)(ws + 16777216);           // 32 MB  [E, HID, DIM] bf16
  uint16_t* w2b = (uint16_t*)(ws + 50331648);           // 32 MB  [E, DIM, HID] bf16
  uint16_t* h   = (uint16_t*)(ws + 83886080);           // 32 MB  [T, HID] bf16
  int* offs     = (int*)(ws + 117440512);               // E+1 ints

  offs_kernel<<<1, 64, 0, stream>>>(cnt, offs);
  cvt_f32_to_bf16<<<1024, 256, 0, stream>>>(x,  xb,  (T_TOK * DIMSZ) / 8);
  cvt_f32_to_bf16<<<2048, 256, 0, stream>>>(w1, w1b, (NEXP * HIDSZ * DIMSZ) / 8);
  cvt_f32_to_bf16<<<2048, 256, 0, stream>>>(w2, w2b, (NEXP * DIMSZ * HIDSZ) / 8);

  // GEMM1: h[t, :] = xb[t, :] @ w1b[e]^T   (N=HID, K=DIM)
  dim3 g1(HIDSZ / 128, NEXP * (T_TOK / 128));
  gemm_grouped<true><<<g1, 256, 0, stream>>>(xb, w1b, (void*)h, offs, HIDSZ, DIMSZ);

  // GEMM2: out[t, :] = h[t, :] @ w2b[e]^T  (N=DIM, K=HID)
  dim3 g2(DIMSZ / 128, NEXP * (T_TOK / 128));
  gemm_grouped<false><<<g2, 256, 0, stream>>>(h, w2b, (void*)out, offs, DIMSZ, HIDSZ);
}

// Round 2
// 289.731 us; speedup vs baseline: 1.0942x; 1.0942x over previous
//
#include <hip/hip_runtime.h>
#include <stdint.h>

#define T_TOK 8192
#define NEXP  8
#define DIMSZ 1024
#define HIDSZ 2048

typedef __attribute__((ext_vector_type(4))) float f32x4;
typedef __attribute__((ext_vector_type(8))) short s16x8;

// ---------- helpers ----------

__device__ __forceinline__ uint16_t f2bf(float f) {
  uint32_t u = __builtin_bit_cast(uint32_t, f);
  u += 0x7fffu + ((u >> 16) & 1u);   // RNE
  return (uint16_t)(u >> 16);
}

// async global->LDS, 16B per lane; LDS dst = wave-uniform base + lane*16.
__device__ __forceinline__ void gload_lds16(const uint16_t* g, const uint16_t* lds_base) {
  __builtin_amdgcn_global_load_lds(
      (const __attribute__((address_space(1))) uint32_t*)(uintptr_t)g,
      (__attribute__((address_space(3))) uint32_t*)(uint32_t)(uintptr_t)lds_base,
      16, 0, 0);
}

// ---------- fused convert (+ offsets in block 0) ----------

__global__ void cvt_all(const float* __restrict__ x, const float* __restrict__ w1,
                        const float* __restrict__ w2, uint16_t* __restrict__ xb,
                        uint16_t* __restrict__ w1b, uint16_t* __restrict__ w2b,
                        const int* __restrict__ counts, int* __restrict__ offs,
                        int* __restrict__ toffs) {
  if (blockIdx.x == 0 && threadIdx.x == 0) {
    int s = 0, ts = 0;
    for (int e = 0; e < NEXP; ++e) {
      offs[e] = s; toffs[e] = ts;
      s += counts[e]; ts += (counts[e] + 127) >> 7;
    }
    offs[NEXP] = s; toffs[NEXP] = ts;
  }
  const int NX = (T_TOK * DIMSZ) / 8;          // uint4 chunks (8 floats each)
  const int NW = (NEXP * HIDSZ * DIMSZ) / 8;
  const int total = NX + 2 * NW;
  const int stride = gridDim.x * blockDim.x;
  for (int i = blockIdx.x * blockDim.x + threadIdx.x; i < total; i += stride) {
    const float* src; uint16_t* dst; int j;
    if (i < NX)           { src = x;  dst = xb;  j = i; }
    else if (i < NX + NW) { src = w1; dst = w1b; j = i - NX; }
    else                  { src = w2; dst = w2b; j = i - NX - NW; }
    const float4* p = (const float4*)src + 2 * (size_t)j;
    float4 a = p[0], b = p[1];
    uint4 o;
    o.x = f2bf(a.x) | ((uint32_t)f2bf(a.y) << 16);
    o.y = f2bf(a.z) | ((uint32_t)f2bf(a.w) << 16);
    o.z = f2bf(b.x) | ((uint32_t)f2bf(b.y) << 16);
    o.w = f2bf(b.z) | ((uint32_t)f2bf(b.w) << 16);
    ((uint4*)dst)[j] = o;
  }
}

// ---------- grouped NT GEMM ----------
// C[m,n] = sum_k A[m,k] * B_e[n,k].  Tile 128x128, BK=32, 4 waves (2x2).
// Compact 1-D grid: block b -> (mtile_global = b>>lognt, nt = b & (NT-1));
// expert found via device tile-offset table (<=71 m-tiles total).
// LDS tiles are chunk-swizzled: global 16B-chunk Q of row R lives at chunk
// Q ^ ((R>>1)&3)  =>  2-way (free) bank access in both staging and ds_read.
template <bool OUT_BF16>
__global__ __launch_bounds__(256, 4)
void gemm_grouped(const uint16_t* __restrict__ A, const uint16_t* __restrict__ B,
                  void* __restrict__ C, const int* __restrict__ offs,
                  const int* __restrict__ toffs, int N, int K, int lognt) {
  __shared__ __align__(16) uint16_t As[128 * 32];  // 8 KB
  __shared__ __align__(16) uint16_t Bs[128 * 32];  // 8 KB

  const int mtg = blockIdx.x >> lognt;
  const int nt  = blockIdx.x & ((1 << lognt) - 1);
  if (mtg >= toffs[NEXP]) return;
  int e = 0;
#pragma unroll
  for (int i = 1; i < NEXP; ++i) e += (toffs[i] <= mtg) ? 1 : 0;
  const int mt      = mtg - toffs[e];
  const int m_start = offs[e];
  const int m_count = offs[e + 1] - m_start;
  const int m0      = mt * 128;
  int valid_m = m_count - m0;
  if (valid_m > 128) valid_m = 128;
  const int n0 = nt * 128;

  const int tid  = threadIdx.x;
  const int w    = tid >> 6;
  const int lane = tid & 63;
  const int wm = w & 1, wn = w >> 1;

  // Staging map (with swizzle): wave w fills 1KB chunks w and w+4.
  // Lane l's 16B lands at LDS row c*16 + (l>>2), chunk position l&3, which
  // holds global chunk Q = (l&3) ^ ((l>>3)&3)  (independent of c).
  const int srow0 = w * 16 + (lane >> 2);
  const int srow1 = (w + 4) * 16 + (lane >> 2);
  const int scol  = (((lane & 3) ^ ((lane >> 3) & 3))) * 8;

  const uint16_t* gA = A + (size_t)m_start * K;
  const uint16_t* gB = B + (size_t)e * N * K;

  const int ar0 = m0 + (srow0 < valid_m ? srow0 : valid_m - 1);
  const int ar1 = m0 + (srow1 < valid_m ? srow1 : valid_m - 1);

  const uint16_t* a0p = gA + (size_t)ar0 * K + scol;
  const uint16_t* a1p = gA + (size_t)ar1 * K + scol;
  const uint16_t* b0p = gB + (size_t)(n0 + srow0) * K + scol;
  const uint16_t* b1p = gB + (size_t)(n0 + srow1) * K + scol;

  const uint16_t* lA0 = &As[w * 512];
  const uint16_t* lA1 = &As[(w + 4) * 512];
  const uint16_t* lB0 = &Bs[w * 512];
  const uint16_t* lB1 = &Bs[(w + 4) * 512];

  // Fragment read (swizzled): row = band + fr, element k-chunk q = lane>>4
  // is at LDS chunk q ^ ((fr>>1)&3)  (independent of the 16-aligned band).
  const int fr  = lane & 15;
  const int fk  = ((lane >> 4) ^ ((fr >> 1) & 3)) * 8;

  f32x4 acc[4][4];
#pragma unroll
  for (int mi = 0; mi < 4; ++mi)
#pragma unroll
    for (int ni = 0; ni < 4; ++ni) acc[mi][ni] = (f32x4){0.f, 0.f, 0.f, 0.f};

  for (int k0 = 0; k0 < K; k0 += 32) {
    __syncthreads();
    gload_lds16(a0p, lA0);
    gload_lds16(a1p, lA1);
    gload_lds16(b0p, lB0);
    gload_lds16(b1p, lB1);
    a0p += 32; a1p += 32; b0p += 32; b1p += 32;
    __syncthreads();

    s16x8 af[4], bf[4];
#pragma unroll
    for (int mi = 0; mi < 4; ++mi)
      af[mi] = *(const s16x8*)&As[(wm * 64 + mi * 16 + fr) * 32 + fk];
#pragma unroll
    for (int ni = 0; ni < 4; ++ni)
      bf[ni] = *(const s16x8*)&Bs[(wn * 64 + ni * 16 + fr) * 32 + fk];
#pragma unroll
    for (int mi = 0; mi < 4; ++mi)
#pragma unroll
      for (int ni = 0; ni < 4; ++ni)
        acc[mi][ni] = __builtin_amdgcn_mfma_f32_16x16x32_bf16(af[mi], bf[ni], acc[mi][ni], 0, 0, 0);
  }

  // Epilogue. C/D 16x16 layout: col = lane&15, row = (lane>>4)*4 + reg.
  const int cq = (lane >> 4) * 4;
  const int cc = lane & 15;
#pragma unroll
  for (int mi = 0; mi < 4; ++mi) {
#pragma unroll
    for (int r = 0; r < 4; ++r) {
      const int rt = wm * 64 + mi * 16 + cq + r;
      if (rt < valid_m) {
        const size_t rowoff = (size_t)(m_start + m0 + rt) * N;
#pragma unroll
        for (int ni = 0; ni < 4; ++ni) {
          const int col = n0 + wn * 64 + ni * 16 + cc;
          const float v = acc[mi][ni][r];
          if (OUT_BF16) {
            ((uint16_t*)C)[rowoff + col] = f2bf(v);
          } else {
            const uint32_t b = (uint32_t)f2bf(v) << 16;
            ((float*)C)[rowoff + col] = __builtin_bit_cast(float, b);
          }
        }
      }
    }
  }
}

// ---------- launch ----------

extern "C" void kernel_launch(void* const* d_in, const int* in_sizes, int n_in,
                              void* d_out, int out_size, void* d_ws, size_t ws_size,
                              hipStream_t stream) {
  const float* x  = (const float*)d_in[0];   // [T, DIM]
  const float* w1 = (const float*)d_in[1];   // [E, HID, DIM]
  const float* w2 = (const float*)d_in[2];   // [E, DIM, HID]
  const int* cnt  = (const int*)d_in[3];     // [E]
  float* out = (float*)d_out;                // [T, DIM] f32

  char* ws = (char*)d_ws;
  uint16_t* xb  = (uint16_t*)(ws);                      // 16 MB  [T, DIM] bf16
  uint16_t* w1b = (uint16_t*)(ws + 16777216);           // 32 MB  [E, HID, DIM] bf16
  uint16_t* w2b = (uint16_t*)(ws + 50331648);           // 32 MB  [E, DIM, HID] bf16
  uint16_t* h   = (uint16_t*)(ws + 83886080);           // 32 MB  [T, HID] bf16
  int* offs     = (int*)(ws + 117440512);               // 9 ints
  int* toffs    = offs + 9;                             // 9 ints

  cvt_all<<<4096, 256, 0, stream>>>(x, w1, w2, xb, w1b, w2b, cnt, offs, toffs);

  const int MAX_MT = T_TOK / 128 + NEXP - 1;            // 71: worst-case m-tiles

  // GEMM1: h = xb @ w1b^T  (N=HID=2048 -> 16 n-tiles, lognt=4, K=DIM)
  gemm_grouped<true><<<MAX_MT * 16, 256, 0, stream>>>(
      xb, w1b, (void*)h, offs, toffs, HIDSZ, DIMSZ, 4);

  // GEMM2: out = h @ w2b^T  (N=DIM=1024 -> 8 n-tiles, lognt=3, K=HID)
  gemm_grouped<false><<<MAX_MT * 8, 256, 0, stream>>>(
      h, w2b, (void*)out, offs, toffs, DIMSZ, HIDSZ, 3);
}